// Round 6
// baseline (166.743 us; speedup 1.0000x reference)
//
#include <hip/hip_runtime.h>

typedef __bf16 bf16x8 __attribute__((ext_vector_type(8)));
typedef float f32x16 __attribute__((ext_vector_type(16)));

#define N_EMB 4096
#define DIM 64
#define NCHUNK 128            // 4096 entries / 32 per chunk
#define NW 8                  // waves per block (chunk-split)
#define CPW (NCHUNK / NW)     // 16 chunks per wave
#define NRS 2                 // rowsets per block (rows held in regs)
#define RPB (NRS * 32)        // 64 rows per block -> 512 blocks, 2 blocks/CU

// ---------------- prep: Wp = bf16(-2W) in A-fragment-linear layout, wnp = ||w||^2
// permuted into the 32x32 C-fragment register order (validated rounds 2-5) ----------------
__global__ void prep_kernel(const float* __restrict__ w, bf16x8* __restrict__ Wp,
                            float* __restrict__ wnp) {
    int id = blockIdx.x * blockDim.x + threadIdx.x;   // 8192 = 128 chunks * 64 lanes
    if (id >= NCHUNK * 64) return;
    int g = id >> 6, l = id & 63;
    int hi = l >> 5;
    const float* wr = w + (size_t)((g << 5) + (l & 31)) * DIM + hi * 8;
    float ss = 0.f;
#pragma unroll
    for (int s = 0; s < 4; ++s) {
        const float4* p = (const float4*)(wr + s * 16);
        float4 v0 = p[0], v1 = p[1];
        ss += v0.x*v0.x + v0.y*v0.y + v0.z*v0.z + v0.w*v0.w;
        ss += v1.x*v1.x + v1.y*v1.y + v1.z*v1.z + v1.w*v1.w;
        bf16x8 o;
        o[0]=(__bf16)(-2.f*v0.x); o[1]=(__bf16)(-2.f*v0.y);
        o[2]=(__bf16)(-2.f*v0.z); o[3]=(__bf16)(-2.f*v0.w);
        o[4]=(__bf16)(-2.f*v1.x); o[5]=(__bf16)(-2.f*v1.y);
        o[6]=(__bf16)(-2.f*v1.z); o[7]=(__bf16)(-2.f*v1.w);
        Wp[(g * 4 + s) * 64 + l] = o;
    }
    ss += __shfl_xor(ss, 32, 64);
    if (l < 32) {
        int h  = (l >> 2) & 1;
        int rr = l - (h << 2);
        int r  = (rr & 7) + ((rr >> 3) << 2);
        wnp[(g << 5) + (h << 4) + r] = ss;
    }
}

// ---------------- main ----------------
__global__ void __launch_bounds__(512, 4) vq_main(   // forces VGPR<=128 -> 4 waves/SIMD
    const float* __restrict__ x, const float* __restrict__ w,
    const bf16x8* __restrict__ Wp, const float* __restrict__ wnp,
    float* __restrict__ qout, float* __restrict__ lout, int nrows) {
    __shared__ float pbest[NW][RPB];
    __shared__ int   sidx[RPB];

    const int tid  = threadIdx.x;
    const int wv   = tid >> 6;
    const int lane = tid & 63;
    const int li   = lane & 31;
    const int hi   = lane >> 5;
    const int rowBase = blockIdx.x * RPB;

    // x B-frags: NRS rowsets of 32 rows, in registers (32 VGPRs)
    bf16x8 xb[NRS][4];
#pragma unroll
    for (int rs = 0; rs < NRS; ++rs) {
        int row = rowBase + rs * 32 + li;
        if (row >= nrows) row = nrows - 1;
#pragma unroll
        for (int s = 0; s < 4; ++s) {
            const float4* p = (const float4*)(x + (size_t)row * DIM + s * 16 + hi * 8);
            float4 v0 = p[0], v1 = p[1];
            bf16x8 v;
            v[0]=(__bf16)v0.x; v[1]=(__bf16)v0.y; v[2]=(__bf16)v0.z; v[3]=(__bf16)v0.w;
            v[4]=(__bf16)v1.x; v[5]=(__bf16)v1.y; v[6]=(__bf16)v1.z; v[7]=(__bf16)v1.w;
            xb[rs][s] = v;
        }
    }

    // packed argmin state: 8 chains per rowset (pair-bit distinguishes r / r+8)
    float pb[NRS][8];
#pragma unroll
    for (int rs = 0; rs < NRS; ++rs)
#pragma unroll
        for (int r = 0; r < 8; ++r) pb[rs][r] = 3.4e38f;

    const int gB  = wv * CPW;
    const int rot = blockIdx.x & (CPW - 1);       // desync the 512-block herd
    #define EFF(i) (gB + (((i) + rot) & (CPW - 1)))

    // loads: A-frags (4x dwordx4/lane) + wnp C-fragment (64B, L1 broadcast)
    #define LOAD(Aa, Wf, g_) do { \
        const bf16x8* ap_ = Wp + (size_t)(g_) * 256 + lane; \
        Aa[0] = ap_[0]; Aa[1] = ap_[64]; Aa[2] = ap_[128]; Aa[3] = ap_[192]; \
        Wf = *(const f32x16*)(wnp + ((g_) << 5) + (hi << 4)); \
    } while (0)

    // distances for one chunk: D = ||w||^2 - 2 x.w  via C-init, then packed argmin
    #define COMPUTE(Aa, Wf, g_) do { \
        const uint32_t tagb_ = ((uint32_t)(g_)) << 1; \
        _Pragma("unroll") \
        for (int rs = 0; rs < NRS; ++rs) { \
            f32x16 acc = __builtin_amdgcn_mfma_f32_32x32x16_bf16(Aa[0], xb[rs][0], Wf, 0, 0, 0); \
            acc = __builtin_amdgcn_mfma_f32_32x32x16_bf16(Aa[1], xb[rs][1], acc, 0, 0, 0); \
            acc = __builtin_amdgcn_mfma_f32_32x32x16_bf16(Aa[2], xb[rs][2], acc, 0, 0, 0); \
            acc = __builtin_amdgcn_mfma_f32_32x32x16_bf16(Aa[3], xb[rs][3], acc, 0, 0, 0); \
            _Pragma("unroll") \
            for (int r = 0; r < 8; ++r) { \
                uint32_t ta_ = (__builtin_bit_cast(uint32_t, acc[r])     & 0xFFFFFF00u) | tagb_; \
                uint32_t tb_ = (__builtin_bit_cast(uint32_t, acc[r + 8]) & 0xFFFFFF00u) | tagb_ | 1u; \
                pb[rs][r] = fminf(fminf(pb[rs][r], __builtin_bit_cast(float, ta_)), \
                                  __builtin_bit_cast(float, tb_)); \
            } \
        } \
    } while (0)

    // depth-2 register pipeline: two buffer pairs in flight
    bf16x8 A0[4], A1[4];
    f32x16 W0, W1;
    LOAD(A0, W0, EFF(0));
    LOAD(A1, W1, EFF(1));
    for (int i = 0; i < CPW; i += 2) {
        COMPUTE(A0, W0, EFF(i));
        if (i + 2 < CPW) LOAD(A0, W0, EFF(i + 2));
        COMPUTE(A1, W1, EFF(i + 1));
        if (i + 3 < CPW) LOAD(A1, W1, EFF(i + 3));
    }

    // per-rowset: merge 8 chains -> entry id; hi-merge; publish
#pragma unroll
    for (int rs = 0; rs < NRS; ++rs) {
        float bv = pb[rs][0];
        int   bc = 0;
#pragma unroll
        for (int r = 1; r < 8; ++r) {
            bool t = pb[rs][r] < bv;
            bv = t ? pb[rs][r] : bv;
            bc = t ? r : bc;
        }
        uint32_t bits = __builtin_bit_cast(uint32_t, bv);
        uint32_t g    = (bits >> 1) & 127u;     // chunk id
        uint32_t rr   = (uint32_t)bc + ((bits & 1u) << 3);   // reg index 0..15
        uint32_t entry = (g << 5) + (rr & 3) + ((rr >> 2) << 3) + ((uint32_t)hi << 2);
        float pv = __builtin_bit_cast(float, (bits & 0xFFFFF000u) | entry);
        float ov = __shfl_xor(pv, 32, 64);
        pv = fminf(pv, ov);
        if (lane < 32) pbest[wv][rs * 32 + li] = pv;
    }
    __syncthreads();

    // cross-wave merge (packed floats -> pure v_min), extract entry
    if (tid < RPB) {
        float m = pbest[0][tid];
#pragma unroll
        for (int q = 1; q < NW; ++q) m = fminf(m, pbest[q][tid]);
        sidx[tid] = (int)(__builtin_bit_cast(uint32_t, m) & 0xFFFu);
    }
    __syncthreads();

    // fused epilogue: gather exact f32 codebook row, write quantized + loss
    {
        int rl = tid >> 3, part = tid & 7;       // 512 threads = 64 rows x 8 parts
        int row = rowBase + rl;
        if (row < nrows) {
            int e = sidx[rl];
            const float4* wr = (const float4*)(w + (size_t)e * DIM + part * 8);
            const float4* xr = (const float4*)(x + (size_t)row * DIM + part * 8);
            float4* qo = (float4*)(qout + (size_t)row * DIM + part * 8);
            float4* lo = (float4*)(lout + (size_t)row * DIM + part * 8);
#pragma unroll
            for (int j = 0; j < 2; ++j) {
                float4 q = wr[j], xv = xr[j], df, qv, lv;
                df.x = q.x - xv.x; df.y = q.y - xv.y; df.z = q.z - xv.z; df.w = q.w - xv.w;
                qv.x = xv.x + df.x; qv.y = xv.y + df.y; qv.z = xv.z + df.z; qv.w = xv.w + df.w;
                float sx = df.x*df.x, sy = df.y*df.y, sz = df.z*df.z, sw = df.w*df.w;
                lv.x = sx + 0.25f*sx; lv.y = sy + 0.25f*sy;
                lv.z = sz + 0.25f*sz; lv.w = sw + 0.25f*sw;
                qo[j] = qv;
                lo[j] = lv;
            }
        }
    }
}

extern "C" void kernel_launch(void* const* d_in, const int* in_sizes, int n_in,
                              void* d_out, int out_size, void* d_ws, size_t ws_size,
                              hipStream_t stream) {
    const float* x = (const float*)d_in[0];   // [8,4096,64] f32
    const float* w = (const float*)d_in[1];   // [4096,64] f32
    const int nrows = in_sizes[0] / DIM;      // 32768
    float* qout = (float*)d_out;
    float* lout = (float*)d_out + (size_t)nrows * DIM;

    // workspace: Wp bf16 fragment-linear (512 KB) | wnp f32 permuted (16 KB)
    bf16x8* Wp  = (bf16x8*)d_ws;
    float*  wnp = (float*)((char*)d_ws + (size_t)N_EMB * DIM * 2);

    prep_kernel<<<(NCHUNK * 64 + 255) / 256, 256, 0, stream>>>(w, Wp, wnp);

    int nb = (nrows + RPB - 1) / RPB;         // 512 blocks, 8 waves each
    vq_main<<<nb, 512, 0, stream>>>(x, w, Wp, wnp, qout, lout, nrows);
}

// Round 7
// 50.378 us; speedup vs baseline: 3.3099x; 3.3099x over previous
//
#include <hip/hip_runtime.h>

typedef __bf16 bf16x8 __attribute__((ext_vector_type(8)));
typedef float f32x16 __attribute__((ext_vector_type(16)));

#define N_EMB 4096
#define DIM 64
#define NCHUNK 128            // 4096 entries / 32 per chunk
#define S_SETS 16             // chunk-sets (8 chunks = 8 waves per set-block)
#define RGROWS 1024           // rows per row-group
#define TPG 32                // 32-row tiles per row-group
#define BIAS 0.0625f          // makes all distances positive -> uint order == float order

// ---------------- prep_w: Wp = bf16(-2W) A-frag-linear; wnp = ||w||^2+BIAS in
// C-frag register order (layouts validated rounds 2-6) ----------------
__global__ void prep_w(const float* __restrict__ w, bf16x8* __restrict__ Wp,
                       float* __restrict__ wnp) {
    int id = blockIdx.x * blockDim.x + threadIdx.x;   // 8192 = 128 chunks * 64 lanes
    if (id >= NCHUNK * 64) return;
    int g = id >> 6, l = id & 63;
    int hi = l >> 5;
    const float* wr = w + (size_t)((g << 5) + (l & 31)) * DIM + hi * 8;
    float ss = 0.f;
#pragma unroll
    for (int s = 0; s < 4; ++s) {
        const float4* p = (const float4*)(wr + s * 16);
        float4 v0 = p[0], v1 = p[1];
        ss += v0.x*v0.x + v0.y*v0.y + v0.z*v0.z + v0.w*v0.w;
        ss += v1.x*v1.x + v1.y*v1.y + v1.z*v1.z + v1.w*v1.w;
        bf16x8 o;
        o[0]=(__bf16)(-2.f*v0.x); o[1]=(__bf16)(-2.f*v0.y);
        o[2]=(__bf16)(-2.f*v0.z); o[3]=(__bf16)(-2.f*v0.w);
        o[4]=(__bf16)(-2.f*v1.x); o[5]=(__bf16)(-2.f*v1.y);
        o[6]=(__bf16)(-2.f*v1.z); o[7]=(__bf16)(-2.f*v1.w);
        Wp[(g * 4 + s) * 64 + l] = o;
    }
    ss += __shfl_xor(ss, 32, 64);
    if (l < 32) {
        int h  = (l >> 2) & 1;
        int rr = l - (h << 2);
        int r  = (rr & 7) + ((rr >> 3) << 2);
        wnp[(g << 5) + (h << 4) + r] = ss + BIAS;
    }
}

// ---------------- prep_x: pack x rows into B-frag-linear bf16 tiles ----------------
// xp[gt*256 + s*64 + l] (bf16x8) = bf16(x[gt*32 + l%32][s*16 + (l/32)*8 + e])
__global__ void prep_x(const float* __restrict__ x, bf16x8* __restrict__ xp,
                       int nrows) {
    int id = blockIdx.x * blockDim.x + threadIdx.x;   // ntiles * 64
    int gt = id >> 6, l = id & 63;
    int row = gt * 32 + (l & 31);
    if (row >= nrows) row = nrows - 1;
    const float* xr = x + (size_t)row * DIM + (l >> 5) * 8;
#pragma unroll
    for (int s = 0; s < 4; ++s) {
        const float4* p = (const float4*)(xr + s * 16);
        float4 v0 = p[0], v1 = p[1];
        bf16x8 o;
        o[0]=(__bf16)v0.x; o[1]=(__bf16)v0.y; o[2]=(__bf16)v0.z; o[3]=(__bf16)v0.w;
        o[4]=(__bf16)v1.x; o[5]=(__bf16)v1.y; o[6]=(__bf16)v1.z; o[7]=(__bf16)v1.w;
        xp[(size_t)gt * 256 + s * 64 + l] = o;
    }
}

// ---------------- main: W-stationary. Wave owns one chunk (regs); streams x tiles ----
__global__ void __launch_bounds__(512) vq_main(
    const bf16x8* __restrict__ Wp, const float* __restrict__ wnp,
    const bf16x8* __restrict__ xp, unsigned int* __restrict__ partial, int nrows) {
    const int tid  = threadIdx.x;
    const int wv   = tid >> 6;
    const int lane = tid & 63;
    const int li   = lane & 31;
    const int hi   = lane >> 5;
    const int b    = blockIdx.x;
    const int set  = b >> 5;                 // b = set*32 + rg  -> XCD = rg%8:
    const int rg   = b & 31;                 // all 16 set-blocks of a slab co-XCD
    const int c    = set * (NCHUNK / S_SETS) + wv;   // this wave's chunk, fixed

    // W fragments: loaded ONCE, register-resident for the whole kernel
    const bf16x8* ap = Wp + (size_t)c * 256 + lane;
    const bf16x8 a0 = ap[0], a1 = ap[64], a2 = ap[128], a3 = ap[192];
    const f32x16 wf = *(const f32x16*)(wnp + (c << 5) + (hi << 4));

    const int tbase = rg * TPG;
    const uint32_t hi4 = (uint32_t)hi << 4;
    unsigned int* pout = partial + (size_t)c * nrows + rg * RGROWS + li;

    #define LOADX(B, t) do { \
        const bf16x8* xpt = xp + (size_t)(tbase + (t)) * 256 + lane; \
        B[0] = xpt[0]; B[1] = xpt[64]; B[2] = xpt[128]; B[3] = xpt[192]; \
    } while (0)

    // one 32-row tile vs this wave's 32 entries: 4 MFMA + tagged uint-min tree
    #define TILE(B, t) do { \
        f32x16 acc = __builtin_amdgcn_mfma_f32_32x32x16_bf16(a0, B[0], wf, 0, 0, 0); \
        acc = __builtin_amdgcn_mfma_f32_32x32x16_bf16(a1, B[1], acc, 0, 0, 0); \
        acc = __builtin_amdgcn_mfma_f32_32x32x16_bf16(a2, B[2], acc, 0, 0, 0); \
        acc = __builtin_amdgcn_mfma_f32_32x32x16_bf16(a3, B[3], acc, 0, 0, 0); \
        uint32_t tb[16]; \
        _Pragma("unroll") \
        for (int r = 0; r < 16; ++r) \
            tb[r] = (__builtin_bit_cast(uint32_t, acc[r]) & 0xFFFFFFE0u) | (uint32_t)r; \
        _Pragma("unroll") \
        for (int st = 8; st > 0; st >>= 1) \
            _Pragma("unroll") \
            for (int j = 0; j < st; ++j) tb[j] = tb[j] < tb[j + st] ? tb[j] : tb[j + st]; \
        uint32_t mb = tb[0] | hi4; \
        uint32_t ob = (uint32_t)__shfl_xor((int)mb, 32, 64); \
        mb = mb < ob ? mb : ob; \
        if (hi == 0) { \
            uint32_t t5 = mb & 31u; \
            uint32_t rr = t5 & 15u, hh = t5 >> 4; \
            uint32_t entry = ((uint32_t)c << 5) + (rr & 3u) + ((rr >> 2) << 3) + (hh << 2); \
            pout[(t) * 32] = (mb & 0xFFFFF000u) | entry; \
        } \
    } while (0)

    bf16x8 xA[4], xB[4];
    LOADX(xA, 0);
    LOADX(xB, 1);
    for (int t = 0; t < TPG; t += 2) {
        TILE(xA, t);
        if (t + 2 < TPG) LOADX(xA, t + 2);
        TILE(xB, t + 1);
        if (t + 3 < TPG) LOADX(xB, t + 3);
    }
    #undef LOADX
    #undef TILE
}

// ---------------- merge: 128-way min per row, gather, epilogue ----------------
__global__ void __launch_bounds__(256) vq_merge(
    const float* __restrict__ x, const float* __restrict__ w,
    const unsigned int* __restrict__ partial,
    float* __restrict__ qout, float* __restrict__ lout, int nrows) {
    __shared__ unsigned int red[4][64];
    __shared__ int sentry[64];
    const int t  = threadIdx.x;
    const int r0 = blockIdx.x * 64;

    {   // phase 1: each thread min-reduces 32 chunks for one row (coalesced)
        int rl = t & 63, cg = t >> 6;
        int row = r0 + rl;
        if (row >= nrows) row = nrows - 1;
        const unsigned int* p = partial + (size_t)(cg * 32) * nrows + row;
        unsigned int m0 = ~0u, m1 = ~0u, m2 = ~0u, m3 = ~0u;
#pragma unroll
        for (int i = 0; i < 32; i += 4) {
            unsigned int v0 = p[(size_t)(i + 0) * nrows];
            unsigned int v1 = p[(size_t)(i + 1) * nrows];
            unsigned int v2 = p[(size_t)(i + 2) * nrows];
            unsigned int v3 = p[(size_t)(i + 3) * nrows];
            m0 = m0 < v0 ? m0 : v0;  m1 = m1 < v1 ? m1 : v1;
            m2 = m2 < v2 ? m2 : v2;  m3 = m3 < v3 ? m3 : v3;
        }
        m0 = m0 < m1 ? m0 : m1;  m2 = m2 < m3 ? m2 : m3;
        red[cg][rl] = m0 < m2 ? m0 : m2;
    }
    __syncthreads();
    if (t < 64) {
        unsigned int a = red[0][t], b = red[1][t], c = red[2][t], d = red[3][t];
        a = a < b ? a : b;  c = c < d ? c : d;
        sentry[t] = (int)((a < c ? a : c) & 0xFFFu);
    }
    __syncthreads();

    {   // phase 2: 64 rows x 4 parts; exact f32 gather + quantized/loss write
        int rl = t >> 2, part = t & 3;
        int row = r0 + rl;
        if (row < nrows) {
            int e = sentry[rl];
            const float4* wr = (const float4*)(w + (size_t)e * DIM + part * 16);
            const float4* xr = (const float4*)(x + (size_t)row * DIM + part * 16);
            float4* qo = (float4*)(qout + (size_t)row * DIM + part * 16);
            float4* lo = (float4*)(lout + (size_t)row * DIM + part * 16);
#pragma unroll
            for (int j = 0; j < 4; ++j) {
                float4 q = wr[j], xv = xr[j], df, qv, lv;
                df.x = q.x - xv.x; df.y = q.y - xv.y; df.z = q.z - xv.z; df.w = q.w - xv.w;
                qv.x = xv.x + df.x; qv.y = xv.y + df.y; qv.z = xv.z + df.z; qv.w = xv.w + df.w;
                float sx = df.x*df.x, sy = df.y*df.y, sz = df.z*df.z, sw = df.w*df.w;
                lv.x = sx + 0.25f*sx; lv.y = sy + 0.25f*sy;
                lv.z = sz + 0.25f*sz; lv.w = sw + 0.25f*sw;
                qo[j] = qv;
                lo[j] = lv;
            }
        }
    }
}

extern "C" void kernel_launch(void* const* d_in, const int* in_sizes, int n_in,
                              void* d_out, int out_size, void* d_ws, size_t ws_size,
                              hipStream_t stream) {
    const float* x = (const float*)d_in[0];   // [8,4096,64] f32
    const float* w = (const float*)d_in[1];   // [4096,64] f32
    const int nrows = in_sizes[0] / DIM;      // 32768
    float* qout = (float*)d_out;
    float* lout = (float*)d_out + (size_t)nrows * DIM;

    // workspace: Wp (512 KB) | wnp (16 KB) | xp (4 MB) | partial (16 MB)
    char* wsp = (char*)d_ws;
    bf16x8* Wp  = (bf16x8*)wsp;                         wsp += (size_t)N_EMB * DIM * 2;
    float*  wnp = (float*)wsp;                          wsp += (size_t)N_EMB * 4;
    bf16x8* xp  = (bf16x8*)wsp;                         wsp += (size_t)nrows * DIM * 2;
    unsigned int* partial = (unsigned int*)wsp;         // NCHUNK * nrows * 4

    prep_w<<<(NCHUNK * 64 + 255) / 256, 256, 0, stream>>>(w, Wp, wnp);

    const int ntiles = nrows / 32;            // 1024
    prep_x<<<(ntiles * 64 + 255) / 256, 256, 0, stream>>>(x, xp, nrows);

    const int nrg = nrows / RGROWS;           // 32
    vq_main<<<S_SETS * nrg, 512, 0, stream>>>(Wp, wnp, xp, partial, nrows);

    vq_merge<<<(nrows + 63) / 64, 256, 0, stream>>>(x, w, partial, qout, lout, nrows);
}

// Round 8
// 41.112 us; speedup vs baseline: 4.0558x; 1.2254x over previous
//
#include <hip/hip_runtime.h>

typedef __bf16 bf16x8 __attribute__((ext_vector_type(8)));
typedef float f32x16 __attribute__((ext_vector_type(16)));

#define N_EMB 4096
#define DIM 64
#define NCHUNK 128            // 4096 entries / 32 per chunk
#define NSETS 8               // codebook sets; block owns one set
#define CPS 16                // chunks per set (16 x 32 = 1024 entries)
#define NW 8                  // waves per block
#define NRS 2                 // rowsets per wave
#define RPW (NRS * 32)        // 64 rows per wave
#define RPB (NW * RPW)        // 512 rows per block
#define BIAS 0.0625f          // |2 x.w| <= 2*12*0.00195 < BIAS -> distances > 0

// ---------------- prep_w: Wp = bf16(-2W) A-frag-linear; wnp = ||w||^2 + BIAS in
// C-frag register order (layouts validated rounds 2-7) ----------------
__global__ void prep_w(const float* __restrict__ w, bf16x8* __restrict__ Wp,
                       float* __restrict__ wnp) {
    int id = blockIdx.x * blockDim.x + threadIdx.x;   // 8192 = 128 chunks * 64 lanes
    if (id >= NCHUNK * 64) return;
    int g = id >> 6, l = id & 63;
    int hi = l >> 5;
    const float* wr = w + (size_t)((g << 5) + (l & 31)) * DIM + hi * 8;
    float ss = 0.f;
#pragma unroll
    for (int s = 0; s < 4; ++s) {
        const float4* p = (const float4*)(wr + s * 16);
        float4 v0 = p[0], v1 = p[1];
        ss += v0.x*v0.x + v0.y*v0.y + v0.z*v0.z + v0.w*v0.w;
        ss += v1.x*v1.x + v1.y*v1.y + v1.z*v1.z + v1.w*v1.w;
        bf16x8 o;
        o[0]=(__bf16)(-2.f*v0.x); o[1]=(__bf16)(-2.f*v0.y);
        o[2]=(__bf16)(-2.f*v0.z); o[3]=(__bf16)(-2.f*v0.w);
        o[4]=(__bf16)(-2.f*v1.x); o[5]=(__bf16)(-2.f*v1.y);
        o[6]=(__bf16)(-2.f*v1.z); o[7]=(__bf16)(-2.f*v1.w);
        Wp[(g * 4 + s) * 64 + l] = o;
    }
    ss += __shfl_xor(ss, 32, 64);
    if (l < 32) {
        int h  = (l >> 2) & 1;
        int rr = l - (h << 2);
        int r  = (rr & 7) + ((rr >> 3) << 2);
        wnp[(g << 5) + (h << 4) + r] = ss + BIAS;
    }
}

// ---------------- main: W-set in LDS (staged once); rows in regs; no loop barriers ----
__device__ __forceinline__ void gload_lds16(const void* g, void* l) {
    __builtin_amdgcn_global_load_lds(
        (const __attribute__((address_space(1))) unsigned int*)g,
        (__attribute__((address_space(3))) unsigned int*)l, 16, 0, 0);
}

__global__ void __launch_bounds__(512) vq_main(
    const bf16x8* __restrict__ Wp, const float* __restrict__ wnp,
    const float* __restrict__ x, unsigned int* __restrict__ partial, int nrows) {
    __shared__ char lds[CPS * 4096 + CPS * 128];   // 64KB A-frags + 2KB wnp frags

    const int tid  = threadIdx.x;
    const int wv   = tid >> 6;
    const int lane = tid & 63;
    const int li   = lane & 31;
    const int hi   = lane >> 5;
    const int set  = blockIdx.x & (NSETS - 1);     // b = rg*8 + set -> XCD b%8 = set
    const int rg   = blockIdx.x >> 3;              //   (set's W-slab L2-resident per XCD)

    // ---- one-time stage: this set's 16 chunks (64KB) + wnp frags (2KB), linear ----
    {
        const char* srcA = (const char*)Wp + (size_t)set * CPS * 4096;
        for (int i = wv; i < CPS * 4; i += NW)     // 64 x 1KB spans, 8 per wave
            gload_lds16(srcA + i * 1024 + lane * 16, lds + i * 1024);
        if (wv == 0) {
            const char* srcW = (const char*)wnp + (size_t)set * CPS * 128;
            gload_lds16(srcW + lane * 16, lds + CPS * 4096);
            gload_lds16(srcW + 1024 + lane * 16, lds + CPS * 4096 + 1024);
        }
    }

    // ---- x B-frags: 2 rowsets of 32 rows, f32 -> bf16, register-resident ----
    bf16x8 xb[NRS][4];
#pragma unroll
    for (int rs = 0; rs < NRS; ++rs) {
        int row = rg * RPB + wv * RPW + rs * 32 + li;
        if (row >= nrows) row = nrows - 1;
#pragma unroll
        for (int s = 0; s < 4; ++s) {
            const float4* p = (const float4*)(x + (size_t)row * DIM + s * 16 + hi * 8);
            float4 v0 = p[0], v1 = p[1];
            bf16x8 v;
            v[0]=(__bf16)v0.x; v[1]=(__bf16)v0.y; v[2]=(__bf16)v0.z; v[3]=(__bf16)v0.w;
            v[4]=(__bf16)v1.x; v[5]=(__bf16)v1.y; v[6]=(__bf16)v1.z; v[7]=(__bf16)v1.w;
            xb[rs][s] = v;
        }
    }

    asm volatile("s_waitcnt vmcnt(0)" ::: "memory");
    __syncthreads();                                // the ONLY barrier

    // packed argmin: 4 chains per rowset; tag byte = (chunk<<2) | member
    float pb[NRS][4];
#pragma unroll
    for (int rs = 0; rs < NRS; ++rs)
#pragma unroll
        for (int q = 0; q < 4; ++q) pb[rs][q] = 3.4e38f;

    for (int c = 0; c < CPS; ++c) {
        const bf16x8* ap = (const bf16x8*)(lds + c * 4096);
        bf16x8 a0 = ap[lane];
        bf16x8 a1 = ap[64 + lane];
        bf16x8 a2 = ap[128 + lane];
        bf16x8 a3 = ap[192 + lane];
        const f32x16 wf = *(const f32x16*)(lds + CPS * 4096 + c * 128 + hi * 64);
        const uint32_t tg = (uint32_t)c << 2;
#pragma unroll
        for (int rs = 0; rs < NRS; ++rs) {
            f32x16 acc = __builtin_amdgcn_mfma_f32_32x32x16_bf16(a0, xb[rs][0], wf, 0, 0, 0);
            acc = __builtin_amdgcn_mfma_f32_32x32x16_bf16(a1, xb[rs][1], acc, 0, 0, 0);
            acc = __builtin_amdgcn_mfma_f32_32x32x16_bf16(a2, xb[rs][2], acc, 0, 0, 0);
            acc = __builtin_amdgcn_mfma_f32_32x32x16_bf16(a3, xb[rs][3], acc, 0, 0, 0);
            // chain q holds regs {q, q+4, q+8, q+12}; member m = r>>2 in tag bits [1:0]
#pragma unroll
            for (int q = 0; q < 4; ++q) {
                float t0 = __builtin_bit_cast(float,
                    (__builtin_bit_cast(uint32_t, acc[q])      & 0xFFFFFF00u) | tg | 0u);
                float t1 = __builtin_bit_cast(float,
                    (__builtin_bit_cast(uint32_t, acc[q + 4])  & 0xFFFFFF00u) | tg | 1u);
                float t2 = __builtin_bit_cast(float,
                    (__builtin_bit_cast(uint32_t, acc[q + 8])  & 0xFFFFFF00u) | tg | 2u);
                float t3 = __builtin_bit_cast(float,
                    (__builtin_bit_cast(uint32_t, acc[q + 12]) & 0xFFFFFF00u) | tg | 3u);
                pb[rs][q] = fminf(fminf(pb[rs][q], t0), fminf(t1, t2));  // v_min3 pair
                pb[rs][q] = fminf(pb[rs][q], t3);
            }
        }
    }

    // per-rowset: merge 4 chains -> entry id; hi-merge; write per-set partial
#pragma unroll
    for (int rs = 0; rs < NRS; ++rs) {
        float bv = pb[rs][0];
        int   bq = 0;
#pragma unroll
        for (int q = 1; q < 4; ++q) {
            bool t = pb[rs][q] < bv;
            bv = t ? pb[rs][q] : bv;
            bq = t ? q : bq;
        }
        uint32_t bits = __builtin_bit_cast(uint32_t, bv);
        uint32_t m    = bits & 3u;
        uint32_t cid  = (bits >> 2) & 15u;
        uint32_t rr   = (uint32_t)bq | (m << 2);                    // reg index 0..15
        uint32_t row_in_chunk = (rr & 3u) + ((rr >> 2) << 3) + ((uint32_t)hi << 2);
        uint32_t entry = (uint32_t)set * 1024 + cid * 32 + row_in_chunk;
        float pv = __builtin_bit_cast(float, (bits & 0xFFFFF000u) | entry);
        float ov = __shfl_xor(pv, 32, 64);   // hi-halves hold complementary entries
        pv = fminf(pv, ov);
        int row = rg * RPB + wv * RPW + rs * 32 + li;
        if (lane < 32 && row < nrows)
            partial[(size_t)set * nrows + row] = __builtin_bit_cast(uint32_t, pv);
    }
}

// ---------------- merge: 8-way min per row, gather, epilogue ----------------
__global__ void __launch_bounds__(256) vq_merge(
    const float* __restrict__ x, const float* __restrict__ w,
    const unsigned int* __restrict__ partial,
    float* __restrict__ qout, float* __restrict__ lout, int nrows) {
    __shared__ int sentry[64];
    const int t  = threadIdx.x;
    const int r0 = blockIdx.x * 64;

    if (t < 64) {
        int row = r0 + t;
        if (row >= nrows) row = nrows - 1;
        unsigned int m = ~0u;
#pragma unroll
        for (int s = 0; s < NSETS; ++s) {
            unsigned int v = partial[(size_t)s * nrows + row];
            m = m < v ? m : v;
        }
        sentry[t] = (int)(m & 0xFFFu);
    }
    __syncthreads();

    {   // 64 rows x 4 parts; exact f32 gather + quantized/loss write
        int rl = t >> 2, part = t & 3;
        int row = r0 + rl;
        if (row < nrows) {
            int e = sentry[rl];
            const float4* wr = (const float4*)(w + (size_t)e * DIM + part * 16);
            const float4* xr = (const float4*)(x + (size_t)row * DIM + part * 16);
            float4* qo = (float4*)(qout + (size_t)row * DIM + part * 16);
            float4* lo = (float4*)(lout + (size_t)row * DIM + part * 16);
#pragma unroll
            for (int j = 0; j < 4; ++j) {
                float4 q = wr[j], xv = xr[j], df, qv, lv;
                df.x = q.x - xv.x; df.y = q.y - xv.y; df.z = q.z - xv.z; df.w = q.w - xv.w;
                qv.x = xv.x + df.x; qv.y = xv.y + df.y; qv.z = xv.z + df.z; qv.w = xv.w + df.w;
                float sx = df.x*df.x, sy = df.y*df.y, sz = df.z*df.z, sw = df.w*df.w;
                lv.x = sx + 0.25f*sx; lv.y = sy + 0.25f*sy;
                lv.z = sz + 0.25f*sz; lv.w = sw + 0.25f*sw;
                qo[j] = qv;
                lo[j] = lv;
            }
        }
    }
}

extern "C" void kernel_launch(void* const* d_in, const int* in_sizes, int n_in,
                              void* d_out, int out_size, void* d_ws, size_t ws_size,
                              hipStream_t stream) {
    const float* x = (const float*)d_in[0];   // [8,4096,64] f32
    const float* w = (const float*)d_in[1];   // [4096,64] f32
    const int nrows = in_sizes[0] / DIM;      // 32768
    float* qout = (float*)d_out;
    float* lout = (float*)d_out + (size_t)nrows * DIM;

    // workspace: Wp (512 KB) | wnp (16 KB) | partial (NSETS * nrows * 4 = 1 MB)
    char* wsp = (char*)d_ws;
    bf16x8* Wp  = (bf16x8*)wsp;                 wsp += (size_t)N_EMB * DIM * 2;
    float*  wnp = (float*)wsp;                  wsp += (size_t)N_EMB * 4;
    unsigned int* partial = (unsigned int*)wsp;

    prep_w<<<(NCHUNK * 64 + 255) / 256, 256, 0, stream>>>(w, Wp, wnp);

    const int nrg = (nrows + RPB - 1) / RPB;    // 64 rowgroups
    vq_main<<<nrg * NSETS, 512, 0, stream>>>(Wp, wnp, x, partial, nrows);

    vq_merge<<<(nrows + 63) / 64, 256, 0, stream>>>(x, w, partial, qout, lout, nrows);
}

// Round 9
// 37.705 us; speedup vs baseline: 4.4223x; 1.0904x over previous
//
#include <hip/hip_runtime.h>

typedef __bf16 bf16x8 __attribute__((ext_vector_type(8)));
typedef float f32x16 __attribute__((ext_vector_type(16)));

#define N_EMB 4096
#define DIM 64
#define NCHUNK 128            // 4096 entries / 32 per chunk
#define NSETS 16              // 16 sets x 8 chunks; block owns one set
#define NW 4                  // waves per block
#define NC 2                  // chunks per wave, register-resident
#define T_TILES 16            // x-tiles (32 rows each) per block
#define BIAS 0.0625f          // w.h.p. |2 x.w| < 0.047 -> distances > 0 (R4-R8 validated)

// ---------------- fused prep: W-pack + a5-norm-frag + x-pack ----------------
// Wp A-frag layout (validated R2-R8): lane l of 32x32x16 holds A[m=l%32][k=8*(l/32)+e]
//   Wp[(g*4+s)*64+l][e] = bf16(-2 * W[g*32+l%32][s*16+(l/32)*8+e])
// a5p: A-operand with A[m][0] = ||W[g*32+m]||^2 + BIAS, else 0 (R5-validated fold)
// xp B-frag layout: xp[gt*256+s*64+l][e] = bf16(x[gt*32+l%32][s*16+(l/32)*8+e])
__global__ void prep(const float* __restrict__ w, const float* __restrict__ x,
                     bf16x8* __restrict__ Wp, bf16x8* __restrict__ a5p,
                     bf16x8* __restrict__ xp, int nrows) {
    int id = blockIdx.x * blockDim.x + threadIdx.x;
    if (id < NCHUNK * 64) {
        int g = id >> 6, l = id & 63;
        int hi = l >> 5;
        const float* wr = w + (size_t)((g << 5) + (l & 31)) * DIM + hi * 8;
        float ss = 0.f;
#pragma unroll
        for (int s = 0; s < 4; ++s) {
            const float4* p = (const float4*)(wr + s * 16);
            float4 v0 = p[0], v1 = p[1];
            ss += v0.x*v0.x + v0.y*v0.y + v0.z*v0.z + v0.w*v0.w;
            ss += v1.x*v1.x + v1.y*v1.y + v1.z*v1.z + v1.w*v1.w;
            bf16x8 o;
            o[0]=(__bf16)(-2.f*v0.x); o[1]=(__bf16)(-2.f*v0.y);
            o[2]=(__bf16)(-2.f*v0.z); o[3]=(__bf16)(-2.f*v0.w);
            o[4]=(__bf16)(-2.f*v1.x); o[5]=(__bf16)(-2.f*v1.y);
            o[6]=(__bf16)(-2.f*v1.z); o[7]=(__bf16)(-2.f*v1.w);
            Wp[(g * 4 + s) * 64 + l] = o;
        }
        ss += __shfl_xor(ss, 32, 64);         // full-row norm
        bf16x8 a5 = {};
        if (l < 32) a5[0] = (__bf16)(ss + BIAS);
        a5p[g * 64 + l] = a5;
    } else {
        int id2 = id - NCHUNK * 64;
        int gt = id2 >> 6, l = id2 & 63;
        if (gt < nrows / 32) {
            int row = gt * 32 + (l & 31);
            const float* xr = x + (size_t)row * DIM + (l >> 5) * 8;
#pragma unroll
            for (int s = 0; s < 4; ++s) {
                const float4* p = (const float4*)(xr + s * 16);
                float4 v0 = p[0], v1 = p[1];
                bf16x8 o;
                o[0]=(__bf16)v0.x; o[1]=(__bf16)v0.y; o[2]=(__bf16)v0.z; o[3]=(__bf16)v0.w;
                o[4]=(__bf16)v1.x; o[5]=(__bf16)v1.y; o[6]=(__bf16)v1.z; o[7]=(__bf16)v1.w;
                xp[(size_t)gt * 256 + s * 64 + l] = o;
            }
        }
    }
}

// ---------------- main: W register-stationary, x-tiles via LDS ring ----------------
__device__ __forceinline__ void gload_lds16(const void* g, void* l) {
    __builtin_amdgcn_global_load_lds(
        (const __attribute__((address_space(1))) unsigned int*)g,
        (__attribute__((address_space(3))) unsigned int*)l, 16, 0, 0);
}
__device__ __forceinline__ unsigned int umin32(unsigned int a, unsigned int b) {
    return a < b ? a : b;
}

__global__ void __launch_bounds__(256) vq_main(
    const bf16x8* __restrict__ Wp, const bf16x8* __restrict__ a5p,
    const bf16x8* __restrict__ xp, unsigned int* __restrict__ partial, int nrows) {
    __shared__ bf16x8 buf[2][256];     // 2 x 4KB x-tile ring

    const int tid  = threadIdx.x;
    const int wv   = tid >> 6;
    const int lane = tid & 63;
    const int li   = lane & 31;
    const int hi   = lane >> 5;
    const int set  = blockIdx.x & (NSETS - 1);     // consecutive blocks -> different sets
    const int rg   = blockIdx.x >> 4;              // row-group

    // ---- W: this wave's 2 chunks, loaded ONCE, register-resident (L2-hot) ----
    bf16x8 a[NC][5];
#pragma unroll
    for (int ck = 0; ck < NC; ++ck) {
        int c = set * (NW * NC) + wv * NC + ck;
        const bf16x8* ap = Wp + (size_t)c * 256 + lane;
        a[ck][0] = ap[0]; a[ck][1] = ap[64]; a[ck][2] = ap[128]; a[ck][3] = ap[192];
        a[ck][4] = a5p[(size_t)c * 64 + lane];
    }
    bf16x8 xone = {};                 // B5 = e_0 (k=0 -> hi==0, e==0)
    if (hi == 0) xone[0] = (__bf16)1.0f;
    const f32x16 zacc = {};

    const int tbase = rg * T_TILES;
    unsigned int* pout = partial + (size_t)(set * NW + wv) * nrows + (size_t)tbase * 32 + li;

    #define STAGE(tt) gload_lds16((const char*)(xp + (size_t)(tbase + (tt)) * 256) + tid * 16, \
                                  (char*)&buf[(tt) & 1][wv * 64])

    STAGE(0);
    asm volatile("s_waitcnt vmcnt(0)" ::: "memory");
    __builtin_amdgcn_s_barrier();

    for (int t = 0; t < T_TILES; ++t) {
        if (t + 1 < T_TILES) STAGE(t + 1);         // into the other buffer
        const bf16x8* bv = &buf[t & 1][0];
        bf16x8 b0 = bv[lane], b1 = bv[64 + lane], b2 = bv[128 + lane], b3 = bv[192 + lane];

        unsigned int best = 0xFFFFFFFFu;
#pragma unroll
        for (int ck = 0; ck < NC; ++ck) {
            // D = (||w||^2+BIAS) - 2 x.w : a5 fold + 4 K-blocks
            f32x16 acc = __builtin_amdgcn_mfma_f32_32x32x16_bf16(a[ck][4], xone, zacc, 0, 0, 0);
            acc = __builtin_amdgcn_mfma_f32_32x32x16_bf16(a[ck][0], b0, acc, 0, 0, 0);
            acc = __builtin_amdgcn_mfma_f32_32x32x16_bf16(a[ck][1], b1, acc, 0, 0, 0);
            acc = __builtin_amdgcn_mfma_f32_32x32x16_bf16(a[ck][2], b2, acc, 0, 0, 0);
            acc = __builtin_amdgcn_mfma_f32_32x32x16_bf16(a[ck][3], b3, acc, 0, 0, 0);
            // tag low 6 bits with (ck,r); positive floats -> uint order == float order
#pragma unroll
            for (int r = 0; r < 16; r += 4) {
                unsigned int t0 = (__builtin_bit_cast(unsigned int, acc[r])     & 0xFFFFFFC0u) | (ck << 4) | r;
                unsigned int t1 = (__builtin_bit_cast(unsigned int, acc[r + 1]) & 0xFFFFFFC0u) | (ck << 4) | (r + 1);
                unsigned int t2 = (__builtin_bit_cast(unsigned int, acc[r + 2]) & 0xFFFFFFC0u) | (ck << 4) | (r + 2);
                unsigned int t3 = (__builtin_bit_cast(unsigned int, acc[r + 3]) & 0xFFFFFFC0u) | (ck << 4) | (r + 3);
                best = umin32(best, umin32(umin32(t0, t1), umin32(t2, t3)));
            }
        }
        best |= (unsigned int)hi << 5;             // hi tag (bit 5 free: ck=bit4, r=bits0-3)
        unsigned int ob = (unsigned int)__shfl_xor((int)best, 32, 64);
        best = umin32(best, ob);
        if (lane < 32) {
            unsigned int r  = best & 15u, ck = (best >> 4) & 1u, hh = (best >> 5) & 1u;
            unsigned int cg = (unsigned int)(set * (NW * NC) + wv * NC) + ck;
            unsigned int entry = cg * 32 + (r & 3u) + ((r >> 2) << 3) + (hh << 2);
            pout[t * 32] = (best & 0xFFFFF000u) | entry;
        }
        // counted wait: issue order this iter = [STAGE(t+1), store(t)];
        // in-order retire -> vmcnt(1) guarantees STAGE(t+1) landed, store may fly.
        if (t + 1 < T_TILES)
            asm volatile("s_waitcnt vmcnt(1)" ::: "memory");
        __builtin_amdgcn_s_barrier();
    }
    #undef STAGE
}

// ---------------- fin: 64-way min per row, gather, epilogue ----------------
__global__ void __launch_bounds__(256) vq_fin(
    const float* __restrict__ x, const float* __restrict__ w,
    const unsigned int* __restrict__ partial,
    float* __restrict__ qout, float* __restrict__ lout, int nrows) {
    __shared__ unsigned int red[4][64];
    __shared__ int sentry[64];
    const int t  = threadIdx.x;
    const int r0 = blockIdx.x * 64;

    {   // phase 1: thread (grp, rl) min-reduces 16 slots for one row (coalesced per slot)
        int rl = t & 63, grp = t >> 6;
        int row = r0 + rl;
        if (row >= nrows) row = nrows - 1;
        const unsigned int* p = partial + (size_t)(grp * 16) * nrows + row;
        unsigned int m = 0xFFFFFFFFu;
#pragma unroll
        for (int s = 0; s < 16; ++s) {
            unsigned int v = p[(size_t)s * nrows];
            m = m < v ? m : v;
        }
        red[grp][rl] = m;
    }
    __syncthreads();
    if (t < 64) {
        unsigned int a = red[0][t], b = red[1][t], c = red[2][t], d = red[3][t];
        a = a < b ? a : b;  c = c < d ? c : d;
        sentry[t] = (int)((a < c ? a : c) & 0xFFFu);
    }
    __syncthreads();

    {   // phase 2: 64 rows x 4 parts; exact f32 gather + quantized/loss write
        int rl = t >> 2, part = t & 3;
        int row = r0 + rl;
        if (row < nrows) {
            int e = sentry[rl];
            const float4* wr = (const float4*)(w + (size_t)e * DIM + part * 16);
            const float4* xr = (const float4*)(x + (size_t)row * DIM + part * 16);
            float4* qo = (float4*)(qout + (size_t)row * DIM + part * 16);
            float4* lo = (float4*)(lout + (size_t)row * DIM + part * 16);
#pragma unroll
            for (int j = 0; j < 4; ++j) {
                float4 q = wr[j], xv = xr[j], df, qv, lv;
                df.x = q.x - xv.x; df.y = q.y - xv.y; df.z = q.z - xv.z; df.w = q.w - xv.w;
                qv.x = xv.x + df.x; qv.y = xv.y + df.y; qv.z = xv.z + df.z; qv.w = xv.w + df.w;
                float sx = df.x*df.x, sy = df.y*df.y, sz = df.z*df.z, sw = df.w*df.w;
                lv.x = sx + 0.25f*sx; lv.y = sy + 0.25f*sy;
                lv.z = sz + 0.25f*sz; lv.w = sw + 0.25f*sw;
                qo[j] = qv;
                lo[j] = lv;
            }
        }
    }
}

extern "C" void kernel_launch(void* const* d_in, const int* in_sizes, int n_in,
                              void* d_out, int out_size, void* d_ws, size_t ws_size,
                              hipStream_t stream) {
    const float* x = (const float*)d_in[0];   // [8,4096,64] f32
    const float* w = (const float*)d_in[1];   // [4096,64] f32
    const int nrows = in_sizes[0] / DIM;      // 32768
    float* qout = (float*)d_out;
    float* lout = (float*)d_out + (size_t)nrows * DIM;

    // ws: Wp 512KB | a5p 128KB | xp 4MB | partial 8MB
    char* wsp = (char*)d_ws;
    bf16x8* Wp  = (bf16x8*)wsp;                 wsp += (size_t)NCHUNK * 256 * 16;
    bf16x8* a5p = (bf16x8*)wsp;                 wsp += (size_t)NCHUNK * 64 * 16;
    bf16x8* xp  = (bf16x8*)wsp;                 wsp += (size_t)nrows * DIM * 2;
    unsigned int* partial = (unsigned int*)wsp; // 64 * nrows * 4

    const int ntiles = nrows / 32;              // 1024
    int prep_thr = NCHUNK * 64 + ntiles * 64;   // 73728
    prep<<<(prep_thr + 255) / 256, 256, 0, stream>>>(w, x, Wp, a5p, xp, nrows);

    const int nrg = nrows / (T_TILES * 32);     // 64
    vq_main<<<NSETS * nrg, 256, 0, stream>>>(Wp, a5p, xp, partial, nrows);

    vq_fin<<<(nrows + 63) / 64, 256, 0, stream>>>(x, w, partial, qout, lout, nrows);
}